// Round 1
// baseline (2558.544 us; speedup 1.0000x reference)
//
#include <hip/hip_runtime.h>
#include <math.h>

#define TT 2048
#define UU 64
#define BB 256

__device__ __forceinline__ float sigmoidf(float x) { return 1.0f / (1.0f + expf(-x)); }

// One block per batch element. 256 threads = 4 waves.
// Thread t: gate g = t>>6 (i,j,f,o), unit u = t&63; owns W0 column c = g*64+u in VGPRs.
// Per step: each wave reads h (64 floats) from its OWN LDS replica (broadcast b128),
// 64 FMAs -> z, z to double-buffered LDS, ONE barrier, then every wave redundantly
// updates (c0,h0) for its lane's unit and rewrites its own h replica (no 2nd barrier).
// Layer 1 (1 unit): wave g butterfly-reduces column g of h.W1; wave 0 consumes it
// one step later (lagged) and stores the dense output.
__global__ __launch_bounds__(256) void lstm_ts_kernel(
    const float* __restrict__ x, const float* __restrict__ W0,
    const float* __restrict__ b0, const float* __restrict__ W1,
    const float* __restrict__ b1, const float* __restrict__ Wd,
    const float* __restrict__ bd, float* __restrict__ out)
{
    __shared__ float xbuf[TT];                       // staged (un-normalized) x row
    __shared__ float zbuf[2][256];                   // double-buffered gate pre-activations
    __shared__ __align__(16) float hbuf[4][UU];      // per-wave h replica
    __shared__ float s1buf[2][4];                    // layer-1 column sums, double-buffered
    __shared__ float red[4];

    const int tid = threadIdx.x;
    const int g = tid >> 6;    // wave id == gate id
    const int u = tid & 63;    // lane id == unit id
    const int b = blockIdx.x;
    const float* xrow = x + b * TT;

    // ---- prologue: stage x, sum of squares over T ----
    float ss = 0.f;
    for (int t = tid; t < TT; t += 256) {
        float v = xrow[t];
        xbuf[t] = v;
        ss += v * v;
    }
    #pragma unroll
    for (int m = 1; m < 64; m <<= 1) ss += __shfl_xor(ss, m, 64);
    if (u == 0) red[g] = ss;
    __syncthreads();
    const float sq = red[0] + red[1] + red[2] + red[3];
    const float scale = 1.0f / sqrtf(fmaxf(sq, 1e-12f));

    // ---- per-thread weights ----
    float wcol[UU];
    #pragma unroll
    for (int k = 0; k < UU; ++k) wcol[k] = W0[(1 + k) * 256 + tid];
    const float wxs = W0[tid] * scale;   // input weight with l2-norm scale folded in
    const float bc  = b0[tid];
    const float w1v = W1[u * 4 + g];     // layer-1 weight for (input unit u, gate g)
    // layer-1 scalar params (held uniformly; only wave 0 uses them)
    const float w1h0 = W1[256 + 0], w1h1 = W1[256 + 1], w1h2 = W1[256 + 2], w1h3 = W1[256 + 3];
    const float b10 = b1[0], b11 = b1[1], b12 = b1[2], b13 = b1[3];
    const float wd = Wd[0], bdv = bd[0];

    // init this wave's h replica to zero (read only by this wave)
    hbuf[g][u] = 0.f;
    const float4* hv4 = reinterpret_cast<const float4*>(&hbuf[g][0]);

    float c0 = 0.f;          // layer-0 cell state for unit u (replicated across waves)
    float h1 = 0.f, c1 = 0.f; // layer-1 state (wave 0)
    __syncthreads();

    for (int t = 0; t < TT; ++t) {
        const int p = t & 1;
        const float xr = xbuf[t];

        // z_c = b + xn*Wx + sum_k h[k]*W[k][c]
        float a0 = 0.f, a1 = 0.f, a2 = 0.f, a3 = 0.f;
        #pragma unroll
        for (int i = 0; i < 16; ++i) {
            float4 h4 = hv4[i];
            a0 = fmaf(h4.x, wcol[4 * i + 0], a0);
            a1 = fmaf(h4.y, wcol[4 * i + 1], a1);
            a2 = fmaf(h4.z, wcol[4 * i + 2], a2);
            a3 = fmaf(h4.w, wcol[4 * i + 3], a3);
        }
        const float z = ((a0 + a1) + (a2 + a3)) + fmaf(xr, wxs, bc);
        zbuf[p][tid] = z;
        __syncthreads();

        // every wave redundantly updates unit u (keeps h replicated, no 2nd barrier)
        const float zi = zbuf[p][u];
        const float zj = zbuf[p][64 + u];
        const float zf = zbuf[p][128 + u];
        const float zo = zbuf[p][192 + u];
        c0 = sigmoidf(zf + 1.0f) * c0 + sigmoidf(zi) * tanhf(zj);
        const float h = sigmoidf(zo) * tanhf(c0);
        hbuf[g][u] = h;

        // layer-1 partial: wave g reduces column g of h.W1
        float pc = h * w1v;
        #pragma unroll
        for (int m = 1; m < 64; m <<= 1) pc += __shfl_xor(pc, m, 64);
        if (u == 0) s1buf[p][g] = pc;

        // wave 0: consume step t-1's layer-1 sums (visible since barrier above)
        if (g == 0 && t > 0) {
            const int q = p ^ 1;
            const float z1i = s1buf[q][0] + h1 * w1h0 + b10;
            const float z1j = s1buf[q][1] + h1 * w1h1 + b11;
            const float z1f = s1buf[q][2] + h1 * w1h2 + b12;
            const float z1o = s1buf[q][3] + h1 * w1h3 + b13;
            c1 = sigmoidf(z1f + 1.0f) * c1 + sigmoidf(z1i) * tanhf(z1j);
            h1 = sigmoidf(z1o) * tanhf(c1);
            if (u == 0) out[b * TT + (t - 1)] = fmaf(h1, wd, bdv);
        }
    }

    // flush the last timestep's layer-1 update
    __syncthreads();
    if (g == 0) {
        const int q = (TT - 1) & 1;
        const float z1i = s1buf[q][0] + h1 * w1h0 + b10;
        const float z1j = s1buf[q][1] + h1 * w1h1 + b11;
        const float z1f = s1buf[q][2] + h1 * w1h2 + b12;
        const float z1o = s1buf[q][3] + h1 * w1h3 + b13;
        c1 = sigmoidf(z1f + 1.0f) * c1 + sigmoidf(z1i) * tanhf(z1j);
        h1 = sigmoidf(z1o) * tanhf(c1);
        if (u == 0) out[b * TT + (TT - 1)] = fmaf(h1, wd, bdv);
    }
}

extern "C" void kernel_launch(void* const* d_in, const int* in_sizes, int n_in,
                              void* d_out, int out_size, void* d_ws, size_t ws_size,
                              hipStream_t stream) {
    const float* x  = (const float*)d_in[0];
    const float* W0 = (const float*)d_in[1];
    const float* b0 = (const float*)d_in[2];
    const float* W1 = (const float*)d_in[3];
    const float* b1 = (const float*)d_in[4];
    const float* Wd = (const float*)d_in[5];
    const float* bd = (const float*)d_in[6];
    float* out = (float*)d_out;
    lstm_ts_kernel<<<BB, 256, 0, stream>>>(x, W0, b0, W1, b1, Wd, bd, out);
}